// Round 7
// baseline (275.610 us; speedup 1.0000x reference)
//
#include <hip/hip_runtime.h>
#include <cstdint>

#define NSEQ 2048
#define DIM  768
#define NH   12
#define HD   64

typedef __attribute__((ext_vector_type(8)))  short bf16x8;
typedef __attribute__((ext_vector_type(4)))  float f32x4;
typedef __attribute__((ext_vector_type(16))) float f32x16;
typedef __attribute__((ext_vector_type(4)))  int   i32x4;
typedef unsigned short u16;

#define MFMA16(a,b,c) __builtin_amdgcn_mfma_f32_16x16x32_bf16(a,b,c,0,0,0)
#define MFMA32(a,b,c) __builtin_amdgcn_mfma_f32_32x32x16_bf16(a,b,c,0,0,0)

// q' = q * HEAD_DIM^-0.5 * log2(e)  -> attention uses exp2 directly
#define QSCALE 0.1803368801111204f

__device__ __forceinline__ u16 f2bf(float f){
  unsigned u = __builtin_bit_cast(unsigned, f);
  return (u16)((u + 0x7fffu + ((u >> 16) & 1u)) >> 16);   // RNE
}
// pack two nonneg floats to bf16x2 (round-half-up, 0.5-ulp; P>=0 only)
__device__ __forceinline__ int pk2bf(float a, float b){
  unsigned ua = (__builtin_bit_cast(unsigned, a) + 0x8000u) >> 16;
  unsigned ub = (__builtin_bit_cast(unsigned, b) + 0x8000u) & 0xffff0000u;
  return (int)(ua | ub);
}

typedef __attribute__((address_space(1))) void gvoid_t;
typedef __attribute__((address_space(3))) void lvoid_t;
__device__ __forceinline__ void g2l16(const void* g, void* l){
  __builtin_amdgcn_global_load_lds((gvoid_t*)g, (lvoid_t*)l, 16, 0, 0);
}

// ---------------------------------------------------------------------------
// Kernel 0: fp32 -> bf16 conversion of x and the three weight matrices.
// ---------------------------------------------------------------------------
__global__ __launch_bounds__(256) void convert_all(
    const float* __restrict__ x,  const float* __restrict__ wq,
    const float* __restrict__ wk, const float* __restrict__ wv,
    u16* __restrict__ xb, u16* __restrict__ wb){
  int blk = blockIdx.x, tid = threadIdx.x;
  const float* src; u16* dst; long idx;
  if (blk < 6144){ src = x; dst = xb; idx = (long)blk*256 + tid; }
  else {
    int r = blk - 6144; int s = r / 576; r -= s*576;
    src = (s==0) ? wq : (s==1) ? wk : wv;
    dst = wb + (long)s * (768*768);
    idx = (long)r*256 + tid;
  }
  float4 v = ((const float4*)src)[idx];
  ushort4 o;
  o.x = f2bf(v.x); o.y = f2bf(v.y); o.z = f2bf(v.z); o.w = f2bf(v.w);
  ((ushort4*)dst)[idx] = o;
}

// ---------------------------------------------------------------------------
// Kernel 1: fused QKV projection GEMM. 128x128 tile, BK=64,
// global_load_lds(16B) + XOR-8 swizzle, 16x16x32 bf16 MFMA, XCD-local bm
// clustering. NEW: Q/K segments use SWAPPED operand order (D = W·X = C^T) so
// each lane holds 4 consecutive out-dims -> ushort4 stores (was 2B scalar).
// V keeps normal order for the V^T store. Outputs: Q (pre-scaled by
// 0.125*log2e), K as [bh][n][64]; V^T [bh][64][n].
// ---------------------------------------------------------------------------
__global__ __launch_bounds__(256,3) void qkv_gemm(
    const u16* __restrict__ xb, const u16* __restrict__ wb,
    const float* __restrict__ bq, const float* __restrict__ bk,
    const float* __restrict__ bv,
    u16* __restrict__ Qo, u16* __restrict__ Ko, u16* __restrict__ Vo){
  __shared__ __align__(16) u16 ldsX[128*64];
  __shared__ __align__(16) u16 ldsW[128*64];
  int tid  = threadIdx.x;
  int w    = tid >> 6, lane = tid & 63;
  int xcd  = blockIdx.x & 7, j = blockIdx.x >> 3;     // j in [0,144)
  int bm   = xcd*8 + j/18, bn = j%18;
  int wm   = w >> 1, wn = w & 1;
  int l15  = lane & 15, g = lane >> 4;
  int srow = lane >> 3;
  int scol = ((lane & 7) ^ srow) * 8;
  int seg  = bn / 6;                                  // 0=Q 1=K 2=V
  bool isv = (seg == 2);

  const u16* xg = xb + (long)bm*128*768;
  const u16* wg = wb + (long)bn*128*768;

  f32x4 acc[4][4] = {};

  for (int k0 = 0; k0 < 768; k0 += 64){
    if (k0) __syncthreads();
    #pragma unroll
    for (int jj = 0; jj < 4; jj++){
      int rr = (w*4 + jj)*8 + srow;
      g2l16(xg + (long)rr*768 + k0 + scol, &ldsX[(w*4 + jj)*512]);
      g2l16(wg + (long)rr*768 + k0 + scol, &ldsW[(w*4 + jj)*512]);
    }
    __syncthreads();
    #pragma unroll
    for (int ks = 0; ks < 2; ks++){
      bf16x8 af[4], bfr[4];
      #pragma unroll
      for (int im = 0; im < 4; im++){
        int row = wm*64 + im*16 + l15;
        af[im] = *(const bf16x8*)&ldsX[row*64 + (((ks*4 + g) ^ (row & 7))*8)];
      }
      #pragma unroll
      for (int in = 0; in < 4; in++){
        int row = wn*64 + in*16 + l15;
        bfr[in] = *(const bf16x8*)&ldsW[row*64 + (((ks*4 + g) ^ (row & 7))*8)];
      }
      if (isv){
        #pragma unroll
        for (int im = 0; im < 4; im++)
          #pragma unroll
          for (int in = 0; in < 4; in++)
            acc[im][in] = MFMA16(af[im], bfr[in], acc[im][in]);
      } else {
        #pragma unroll
        for (int im = 0; im < 4; im++)
          #pragma unroll
          for (int in = 0; in < 4; in++)
            acc[im][in] = MFMA16(bfr[in], af[im], acc[im][in]);
      }
    }
  }

  const float* bias = (seg==0) ? bq : (seg==1) ? bk : bv;
  if (isv){
    // acc: col=l15=o, row=g*4+reg=t  -> V^T [bh][d][n] ushort4 along n
    #pragma unroll
    for (int in = 0; in < 4; in++){
      int o  = bn*128 + wn*64 + in*16 + l15;
      int oo = o - 2*768;
      int h  = oo >> 6, d = oo & 63;
      float bb = bias[oo];
      #pragma unroll
      for (int im = 0; im < 4; im++){
        int t  = bm*128 + wm*64 + im*16 + g*4;
        int bi = t >> 11, n0 = t & 2047;
        f32x4 a = acc[im][in];
        ushort4 pk;
        pk.x = f2bf(a[0] + bb); pk.y = f2bf(a[1] + bb);
        pk.z = f2bf(a[2] + bb); pk.w = f2bf(a[3] + bb);
        *(ushort4*)&Vo[((long)(bi*NH + h)*HD + d)*NSEQ + n0] = pk;
      }
    }
  } else {
    // swapped: col=l15=t, row=g*4+reg=o -> lane has 4 consecutive out-dims
    u16* dst = (seg==0) ? Qo : Ko;
    float sc = (seg==0) ? QSCALE : 1.0f;
    #pragma unroll
    for (int im = 0; im < 4; im++){
      int t  = bm*128 + wm*64 + im*16 + l15;
      int bi = t >> 11, n0 = t & 2047;
      #pragma unroll
      for (int in = 0; in < 4; in++){
        int oo = bn*128 + wn*64 + in*16 + g*4 - seg*768;
        int h  = oo >> 6, d0 = oo & 63;
        float4 bb = *(const float4*)&bias[oo];
        f32x4 a = acc[im][in];
        ushort4 pk;
        pk.x = f2bf((a[0] + bb.x)*sc); pk.y = f2bf((a[1] + bb.y)*sc);
        pk.z = f2bf((a[2] + bb.z)*sc); pk.w = f2bf((a[3] + bb.w)*sc);
        *(ushort4*)&dst[((long)(bi*NH + h)*NSEQ + n0)*HD + d0] = pk;
      }
    }
  }
}

// ---------------------------------------------------------------------------
// Kernel 2: flash attention fwd, 32x32-MFMA pipeline with LANE-LOCAL P
// transform. Key insight: with Sᵀ from mfma_32x32x16 (C: col=q-row=lane&31,
// row=key=(reg&3)+8*(reg>>2)+4*(lane>>5)), the PV B-operand fragment for a
// 16-key window (B: k=(lane>>5)*8+j, n=lane&31) is exactly reg-quad
// (2*kc + lane>>5) exchanged between lane pairs (l31, l31^32): 2 shfl_xor +
// 6 selects per chunk. NO LDS round-trip for P at all.
// Block = 4 waves x 32 q-rows of one head (XCD-pinned: K+V L2-resident);
// K/V staged to LDS double-buffered (R5-verified XOR-8 16B swizzle),
// conflict-free b128 fragment reads for both QK (A=K) and PV (A=V^T).
// No-max streaming softmax; l is fully lane-local until ONE final shuffle.
// ---------------------------------------------------------------------------
__global__ __launch_bounds__(256,4) void attn(
    const u16* __restrict__ Q, const u16* __restrict__ K,
    const u16* __restrict__ VT, float* __restrict__ out){
  __shared__ __align__(16) u16 kls[2][64*64];   // [key][d]   8KB per buf
  __shared__ __align__(16) u16 vls[2][64*64];   // [d][key]   8KB per buf
  int tid = threadIdx.x;
  int w   = tid >> 6, lane = tid & 63;
  int xcd = blockIdx.x & 7, j = blockIdx.x >> 3;   // j in [0,96)
  int bh  = xcd*6 + (j >> 4), qc = j & 15;
  int b   = bh / NH, h = bh - b*NH;
  int l31 = lane & 31, hi = lane >> 5;
  int srow = lane >> 3;
  int scol = ((lane & 7) ^ srow) * 8;

  const u16* Qb = Q  + (long)bh*NSEQ*HD;
  const u16* Kb = K  + (long)bh*NSEQ*HD;
  const u16* Vb = VT + (long)bh*HD*NSEQ;

  int r0 = qc*128 + w*32;
  // Q fragments (B-operand of 32x32x16: k=hi*8+j within 16-d window dk)
  bf16x8 qf[4];
  {
    const u16* qrow = Qb + (long)(r0 + l31)*HD;
    #pragma unroll
    for (int dk = 0; dk < 4; dk++)
      qf[dk] = *(const bf16x8*)&qrow[dk*16 + hi*8];
  }

  f32x16 oa[2] = {};            // O^T [d-tile of 32][r=32]
  float ls = 0.f;               // lane-local row sum (q-row = l31)

#define STAGE(c0, bf)                                                         \
  {                                                                           \
    _Pragma("unroll")                                                         \
    for (int jj = 0; jj < 2; jj++){                                           \
      int rr = jj*32 + w*8;                                                   \
      g2l16(Kb + (long)((c0) + rr + srow)*HD + scol,  &kls[bf][rr*64]);       \
      g2l16(Vb + (long)(rr + srow)*NSEQ + (c0) + scol, &vls[bf][rr*64]);      \
    }                                                                         \
  }

  // one 32-key window: Sᵀ = K·Qᵀ -> exp2 -> lane-local pack/exchange -> PV
#define KH(bf, kh)                                                            \
  {                                                                           \
    bf16x8 kf[4];                                                             \
    _Pragma("unroll")                                                         \
    for (int dk = 0; dk < 4; dk++)                                            \
      kf[dk] = *(const bf16x8*)                                               \
        &kls[bf][((kh)*32 + l31)*64 + (((dk*2 + hi) ^ (l31 & 7))*8)];         \
    f32x16 T = {};                                                            \
    _Pragma("unroll")                                                         \
    for (int dk = 0; dk < 4; dk++)                                            \
      T = MFMA32(kf[dk], qf[dk], T);                                          \
    int PD[4][2];                                                             \
    _Pragma("unroll")                                                         \
    for (int q = 0; q < 4; q++){                                              \
      float p0 = __builtin_amdgcn_exp2f(T[q*4+0]);                            \
      float p1 = __builtin_amdgcn_exp2f(T[q*4+1]);                            \
      float p2 = __builtin_amdgcn_exp2f(T[q*4+2]);                            \
      float p3 = __builtin_amdgcn_exp2f(T[q*4+3]);                            \
      ls += (p0 + p1) + (p2 + p3);                                            \
      PD[q][0] = pk2bf(p0, p1);                                               \
      PD[q][1] = pk2bf(p2, p3);                                               \
    }                                                                         \
    _Pragma("unroll")                                                         \
    for (int kc = 0; kc < 2; kc++){                                           \
      int s0 = hi ? PD[2*kc][0] : PD[2*kc+1][0];                              \
      int s1 = hi ? PD[2*kc][1] : PD[2*kc+1][1];                              \
      int x0 = __shfl_xor(s0, 32);                                            \
      int x1 = __shfl_xor(s1, 32);                                            \
      i32x4 pr;                                                               \
      pr[0] = hi ? x0 : PD[2*kc][0];                                          \
      pr[1] = hi ? x1 : PD[2*kc][1];                                          \
      pr[2] = hi ? PD[2*kc+1][0] : x0;                                        \
      pr[3] = hi ? PD[2*kc+1][1] : x1;                                        \
      bf16x8 pf = __builtin_bit_cast(bf16x8, pr);                             \
      _Pragma("unroll")                                                       \
      for (int dt = 0; dt < 2; dt++){                                         \
        bf16x8 vf = *(const bf16x8*)                                          \
          &vls[bf][(dt*32 + l31)*64 + ((((kh)*4 + kc*2 + hi) ^ (l31 & 7))*8)];\
        oa[dt] = MFMA32(vf, pf, oa[dt]);                                      \
      }                                                                       \
    }                                                                         \
  }

  STAGE(0, 0);
  __syncthreads();
  for (int i = 0; i < 32; i++){
    int cb = i & 1, nb = cb ^ 1;
    STAGE(((i+1) & 31)*64, nb);       // wraps to tile 0 on last iter (safe)
    KH(cb, 0);
    KH(cb, 1);
    __syncthreads();                  // drains our g2l16s + syncs consumers
  }
#undef STAGE
#undef KH

  // finish row sum: partner lane holds the complementary keys of row l31
  ls += __shfl_xor(ls, 32);
  float inv = 1.f / ls;

  // O^T: col=r=l31, row=d=(reg&3)+8*(reg>>2)+4*hi (+32*dt) -> float4 stores
  float* op = &out[(long)(b*NSEQ + r0 + l31)*DIM + h*HD];
  #pragma unroll
  for (int dt = 0; dt < 2; dt++)
    #pragma unroll
    for (int rq = 0; rq < 4; rq++){
      f32x4 v;
      v[0] = oa[dt][rq*4+0]; v[1] = oa[dt][rq*4+1];
      v[2] = oa[dt][rq*4+2]; v[3] = oa[dt][rq*4+3];
      v *= inv;
      *(f32x4*)&op[dt*32 + rq*8 + hi*4] = v;
    }
}

// ---------------------------------------------------------------------------
extern "C" void kernel_launch(void* const* d_in, const int* in_sizes, int n_in,
                              void* d_out, int out_size, void* d_ws, size_t ws_size,
                              hipStream_t stream){
  (void)in_sizes; (void)n_in; (void)out_size; (void)ws_size;
  const float* x  = (const float*)d_in[0];
  const float* wq = (const float*)d_in[1];
  const float* bq = (const float*)d_in[2];
  const float* wk = (const float*)d_in[3];
  const float* bk = (const float*)d_in[4];
  const float* wv = (const float*)d_in[5];
  const float* bv = (const float*)d_in[6];

  char* ws = (char*)d_ws;
  u16* xb = (u16*)ws;                       // [8192][768]
  u16* wb = (u16*)(ws + 12582912);          // [2304][768]
  u16* Qp = (u16*)(ws + 16121856);          // [48][2048][64]
  u16* Kp = (u16*)(ws + 28704768);          // [48][2048][64]
  u16* Vp = (u16*)(ws + 41287680);          // [48][64][2048]  (V^T)

  convert_all<<<7872, 256, 0, stream>>>(x, wq, wk, wv, xb, wb);
  qkv_gemm<<<1152, 256, 0, stream>>>(xb, wb, bq, bk, bv, Qp, Kp, Vp);
  attn<<<768, 256, 0, stream>>>(Qp, Kp, Vp, (float*)d_out);
}

// Round 8
// 203.239 us; speedup vs baseline: 1.3561x; 1.3561x over previous
//
#include <hip/hip_runtime.h>
#include <cstdint>

#define NSEQ 2048
#define DIM  768
#define NH   12
#define HD   64

typedef __attribute__((ext_vector_type(8)))  short bf16x8;
typedef __attribute__((ext_vector_type(4)))  float f32x4;
typedef __attribute__((ext_vector_type(16))) float f32x16;
typedef __attribute__((ext_vector_type(4)))  int   i32x4;
typedef unsigned short u16;

#define MFMA16(a,b,c) __builtin_amdgcn_mfma_f32_16x16x32_bf16(a,b,c,0,0,0)
#define MFMA32(a,b,c) __builtin_amdgcn_mfma_f32_32x32x16_bf16(a,b,c,0,0,0)

// q' = q * HEAD_DIM^-0.5 * log2(e)  -> attention uses exp2 directly
#define QSCALE 0.1803368801111204f

__device__ __forceinline__ u16 f2bf(float f){
  unsigned u = __builtin_bit_cast(unsigned, f);
  return (u16)((u + 0x7fffu + ((u >> 16) & 1u)) >> 16);   // RNE
}
// pack two nonneg floats to bf16x2 (round-half-up, 0.5-ulp; P>=0 only)
__device__ __forceinline__ int pk2bf(float a, float b){
  unsigned ua = (__builtin_bit_cast(unsigned, a) + 0x8000u) >> 16;
  unsigned ub = (__builtin_bit_cast(unsigned, b) + 0x8000u) & 0xffff0000u;
  return (int)(ua | ub);
}

typedef __attribute__((address_space(1))) void gvoid_t;
typedef __attribute__((address_space(3))) void lvoid_t;
__device__ __forceinline__ void g2l16(const void* g, void* l){
  __builtin_amdgcn_global_load_lds((gvoid_t*)g, (lvoid_t*)l, 16, 0, 0);
}

// ---------------------------------------------------------------------------
// Kernel 0: fp32 -> bf16 conversion of x and the three weight matrices.
// ---------------------------------------------------------------------------
__global__ __launch_bounds__(256) void convert_all(
    const float* __restrict__ x,  const float* __restrict__ wq,
    const float* __restrict__ wk, const float* __restrict__ wv,
    u16* __restrict__ xb, u16* __restrict__ wb){
  int blk = blockIdx.x, tid = threadIdx.x;
  const float* src; u16* dst; long idx;
  if (blk < 6144){ src = x; dst = xb; idx = (long)blk*256 + tid; }
  else {
    int r = blk - 6144; int s = r / 576; r -= s*576;
    src = (s==0) ? wq : (s==1) ? wk : wv;
    dst = wb + (long)s * (768*768);
    idx = (long)r*256 + tid;
  }
  float4 v = ((const float4*)src)[idx];
  ushort4 o;
  o.x = f2bf(v.x); o.y = f2bf(v.y); o.z = f2bf(v.z); o.w = f2bf(v.w);
  ((ushort4*)dst)[idx] = o;
}

// ---------------------------------------------------------------------------
// Kernel 1: fused QKV projection GEMM — EXACT R5 version (measured-good).
// 128x128 tile, BK=64, global_load_lds(16B) + XOR-8 swizzle, 16x16x32 bf16
// MFMA (single operand order, no branch in K-loop), XCD-local bm clustering.
// R7's swapped-operand wide-store epilogue caused 252MB HBM writes (6.6x
// amplification) and made the kernel write-bound — reverted.
// Outputs: Q (pre-scaled by 0.125*log2e), K as [bh][n][64]; V^T [bh][64][n].
// ---------------------------------------------------------------------------
__global__ __launch_bounds__(256,3) void qkv_gemm(
    const u16* __restrict__ xb, const u16* __restrict__ wb,
    const float* __restrict__ bq, const float* __restrict__ bk,
    const float* __restrict__ bv,
    u16* __restrict__ Qo, u16* __restrict__ Ko, u16* __restrict__ Vo){
  __shared__ __align__(16) u16 ldsX[128*64];
  __shared__ __align__(16) u16 ldsW[128*64];
  int tid  = threadIdx.x;
  int w    = tid >> 6, lane = tid & 63;
  int xcd  = blockIdx.x & 7, j = blockIdx.x >> 3;     // j in [0,144)
  int bm   = xcd*8 + j/18, bn = j%18;
  int wm   = w >> 1, wn = w & 1;
  int l15  = lane & 15, g = lane >> 4;
  int srow = lane >> 3;
  int scol = ((lane & 7) ^ srow) * 8;

  const u16* xg = xb + (long)bm*128*768;
  const u16* wg = wb + (long)bn*128*768;

  f32x4 acc[4][4] = {};

  for (int k0 = 0; k0 < 768; k0 += 64){
    if (k0) __syncthreads();
    #pragma unroll
    for (int jj = 0; jj < 4; jj++){
      int rr = (w*4 + jj)*8 + srow;
      g2l16(xg + (long)rr*768 + k0 + scol, &ldsX[(w*4 + jj)*512]);
      g2l16(wg + (long)rr*768 + k0 + scol, &ldsW[(w*4 + jj)*512]);
    }
    __syncthreads();
    #pragma unroll
    for (int ks = 0; ks < 2; ks++){
      bf16x8 af[4], bfr[4];
      #pragma unroll
      for (int im = 0; im < 4; im++){
        int row = wm*64 + im*16 + l15;
        af[im] = *(const bf16x8*)&ldsX[row*64 + (((ks*4 + g) ^ (row & 7))*8)];
      }
      #pragma unroll
      for (int in = 0; in < 4; in++){
        int row = wn*64 + in*16 + l15;
        bfr[in] = *(const bf16x8*)&ldsW[row*64 + (((ks*4 + g) ^ (row & 7))*8)];
      }
      #pragma unroll
      for (int im = 0; im < 4; im++)
        #pragma unroll
        for (int in = 0; in < 4; in++)
          acc[im][in] = MFMA16(af[im], bfr[in], acc[im][in]);
    }
  }

  int seg = bn / 6;
  const float* bias = (seg==0) ? bq : (seg==1) ? bk : bv;
  #pragma unroll
  for (int in = 0; in < 4; in++){
    int o  = bn*128 + wn*64 + in*16 + l15;
    int oo = o - seg*768;
    int h  = oo >> 6, d = oo & 63;
    float bb = bias[oo];
    #pragma unroll
    for (int im = 0; im < 4; im++){
      int t  = bm*128 + wm*64 + im*16 + g*4;
      int bi = t >> 11, n0 = t & 2047;
      f32x4 a = acc[im][in];
      if (seg == 2){
        ushort4 pk;
        pk.x = f2bf(a[0] + bb); pk.y = f2bf(a[1] + bb);
        pk.z = f2bf(a[2] + bb); pk.w = f2bf(a[3] + bb);
        *(ushort4*)&Vo[((long)(bi*NH + h)*HD + d)*NSEQ + n0] = pk;   // V^T
      } else if (seg == 0){
        #pragma unroll
        for (int r = 0; r < 4; r++)
          Qo[((long)(bi*NH + h)*NSEQ + n0 + r)*HD + d] = f2bf((a[r] + bb)*QSCALE);
      } else {
        #pragma unroll
        for (int r = 0; r < 4; r++)
          Ko[((long)(bi*NH + h)*NSEQ + n0 + r)*HD + d] = f2bf(a[r] + bb);
      }
    }
  }
}

// ---------------------------------------------------------------------------
// Kernel 2: flash attention fwd, 32x32-MFMA pipeline with LANE-LOCAL P
// transform (R7 structure; launch bounds relaxed to 3 blocks/CU so the
// ~120-130 VGPR live set doesn't spill under the 128-VGPR cap of 4/CU).
// Sᵀ via mfma_32x32x16 (C: col=q-row=lane&31, key=(reg&3)+8*(reg>>2)+
// 4*(lane>>5)); PV B-fragment for a 16-key window = reg-quad (2*kc+hi)
// exchanged between lane pairs (l31, l31^32): 2 shfl_xor + selects, no LDS.
// Block = 4 waves x 32 q-rows of one head (XCD-pinned: K+V L2-resident);
// K/V staged to LDS double-buffered (XOR-8 16B swizzle, conflict-free b128).
// No-max streaming softmax; l lane-local until ONE final shuffle.
// ---------------------------------------------------------------------------
__global__ __launch_bounds__(256,3) void attn(
    const u16* __restrict__ Q, const u16* __restrict__ K,
    const u16* __restrict__ VT, float* __restrict__ out){
  __shared__ __align__(16) u16 kls[2][64*64];   // [key][d]   8KB per buf
  __shared__ __align__(16) u16 vls[2][64*64];   // [d][key]   8KB per buf
  int tid = threadIdx.x;
  int w   = tid >> 6, lane = tid & 63;
  int xcd = blockIdx.x & 7, j = blockIdx.x >> 3;   // j in [0,96)
  int bh  = xcd*6 + (j >> 4), qc = j & 15;
  int b   = bh / NH, h = bh - b*NH;
  int l31 = lane & 31, hi = lane >> 5;
  int srow = lane >> 3;
  int scol = ((lane & 7) ^ srow) * 8;

  const u16* Qb = Q  + (long)bh*NSEQ*HD;
  const u16* Kb = K  + (long)bh*NSEQ*HD;
  const u16* Vb = VT + (long)bh*HD*NSEQ;

  int r0 = qc*128 + w*32;
  // Q fragments (B-operand of 32x32x16: k=hi*8+j within 16-d window dk)
  bf16x8 qf[4];
  {
    const u16* qrow = Qb + (long)(r0 + l31)*HD;
    #pragma unroll
    for (int dk = 0; dk < 4; dk++)
      qf[dk] = *(const bf16x8*)&qrow[dk*16 + hi*8];
  }

  f32x16 oa[2] = {};            // O^T [d-tile of 32][r=32]
  float ls = 0.f;               // lane-local row sum (q-row = l31)

#define STAGE(c0, bf)                                                         \
  {                                                                           \
    _Pragma("unroll")                                                         \
    for (int jj = 0; jj < 2; jj++){                                           \
      int rr = jj*32 + w*8;                                                   \
      g2l16(Kb + (long)((c0) + rr + srow)*HD + scol,  &kls[bf][rr*64]);       \
      g2l16(Vb + (long)(rr + srow)*NSEQ + (c0) + scol, &vls[bf][rr*64]);      \
    }                                                                         \
  }

  // one 32-key window: Sᵀ = K·Qᵀ -> exp2 -> lane-local pack/exchange -> PV
#define KH(bf, kh)                                                            \
  {                                                                           \
    bf16x8 kf[4];                                                             \
    _Pragma("unroll")                                                         \
    for (int dk = 0; dk < 4; dk++)                                            \
      kf[dk] = *(const bf16x8*)                                               \
        &kls[bf][((kh)*32 + l31)*64 + (((dk*2 + hi) ^ (l31 & 7))*8)];         \
    f32x16 T = {};                                                            \
    _Pragma("unroll")                                                         \
    for (int dk = 0; dk < 4; dk++)                                            \
      T = MFMA32(kf[dk], qf[dk], T);                                          \
    int PD[4][2];                                                             \
    _Pragma("unroll")                                                         \
    for (int q = 0; q < 4; q++){                                              \
      float p0 = __builtin_amdgcn_exp2f(T[q*4+0]);                            \
      float p1 = __builtin_amdgcn_exp2f(T[q*4+1]);                            \
      float p2 = __builtin_amdgcn_exp2f(T[q*4+2]);                            \
      float p3 = __builtin_amdgcn_exp2f(T[q*4+3]);                            \
      ls += (p0 + p1) + (p2 + p3);                                            \
      PD[q][0] = pk2bf(p0, p1);                                               \
      PD[q][1] = pk2bf(p2, p3);                                               \
    }                                                                         \
    _Pragma("unroll")                                                         \
    for (int kc = 0; kc < 2; kc++){                                           \
      int s0 = hi ? PD[2*kc][0] : PD[2*kc+1][0];                              \
      int s1 = hi ? PD[2*kc][1] : PD[2*kc+1][1];                              \
      int x0 = __shfl_xor(s0, 32);                                            \
      int x1 = __shfl_xor(s1, 32);                                            \
      i32x4 pr;                                                               \
      pr[0] = hi ? x0 : PD[2*kc][0];                                          \
      pr[1] = hi ? x1 : PD[2*kc][1];                                          \
      pr[2] = hi ? PD[2*kc+1][0] : x0;                                        \
      pr[3] = hi ? PD[2*kc+1][1] : x1;                                        \
      bf16x8 pf = __builtin_bit_cast(bf16x8, pr);                             \
      _Pragma("unroll")                                                       \
      for (int dt = 0; dt < 2; dt++){                                         \
        bf16x8 vf = *(const bf16x8*)                                          \
          &vls[bf][(dt*32 + l31)*64 + ((((kh)*4 + kc*2 + hi) ^ (l31 & 7))*8)];\
        oa[dt] = MFMA32(vf, pf, oa[dt]);                                      \
      }                                                                       \
    }                                                                         \
  }

  STAGE(0, 0);
  __syncthreads();
  for (int i = 0; i < 32; i++){
    int cb = i & 1, nb = cb ^ 1;
    STAGE(((i+1) & 31)*64, nb);       // wraps to tile 0 on last iter (safe)
    KH(cb, 0);
    KH(cb, 1);
    __syncthreads();                  // drains our g2l16s + syncs consumers
  }
#undef STAGE
#undef KH

  // finish row sum: partner lane holds the complementary keys of row l31
  ls += __shfl_xor(ls, 32);
  float inv = 1.f / ls;

  // O^T: col=r=l31, row=d=(reg&3)+8*(reg>>2)+4*hi (+32*dt) -> float4 stores
  float* op = &out[(long)(b*NSEQ + r0 + l31)*DIM + h*HD];
  #pragma unroll
  for (int dt = 0; dt < 2; dt++)
    #pragma unroll
    for (int rq = 0; rq < 4; rq++){
      f32x4 v;
      v[0] = oa[dt][rq*4+0]; v[1] = oa[dt][rq*4+1];
      v[2] = oa[dt][rq*4+2]; v[3] = oa[dt][rq*4+3];
      v *= inv;
      *(f32x4*)&op[dt*32 + rq*8 + hi*4] = v;
    }
}

// ---------------------------------------------------------------------------
extern "C" void kernel_launch(void* const* d_in, const int* in_sizes, int n_in,
                              void* d_out, int out_size, void* d_ws, size_t ws_size,
                              hipStream_t stream){
  (void)in_sizes; (void)n_in; (void)out_size; (void)ws_size;
  const float* x  = (const float*)d_in[0];
  const float* wq = (const float*)d_in[1];
  const float* bq = (const float*)d_in[2];
  const float* wk = (const float*)d_in[3];
  const float* bk = (const float*)d_in[4];
  const float* wv = (const float*)d_in[5];
  const float* bv = (const float*)d_in[6];

  char* ws = (char*)d_ws;
  u16* xb = (u16*)ws;                       // [8192][768]
  u16* wb = (u16*)(ws + 12582912);          // [2304][768]
  u16* Qp = (u16*)(ws + 16121856);          // [48][2048][64]
  u16* Kp = (u16*)(ws + 28704768);          // [48][2048][64]
  u16* Vp = (u16*)(ws + 41287680);          // [48][64][2048]  (V^T)

  convert_all<<<7872, 256, 0, stream>>>(x, wq, wk, wv, xb, wb);
  qkv_gemm<<<1152, 256, 0, stream>>>(xb, wb, bq, bk, bv, Qp, Kp, Vp);
  attn<<<768, 256, 0, stream>>>(Qp, Kp, Vp, (float*)d_out);
}